// Round 6
// baseline (175.607 us; speedup 1.0000x reference)
//
#include <hip/hip_runtime.h>
#include <hip/hip_bf16.h>
#include <hip/hip_cooperative_groups.h>
#include <math.h>

namespace cg = cooperative_groups;

#define EPS 1e-8f

constexpr int Bb = 8, Nn = 2048, Hh = 128;
constexpr int BN = Bb * Nn;      // 16384 rows per tensor

typedef __attribute__((ext_vector_type(8))) short bf16x8;
typedef __attribute__((ext_vector_type(4))) float f32x4;

#define MFMA16(a, b, c) __builtin_amdgcn_mfma_f32_16x16x32_bf16(a, b, c, 0, 0, 0)

static __device__ __forceinline__ ushort f2bf(float f) {
  union { __hip_bfloat16 h; ushort s; } u;
  u.h = __float2bfloat16(f);   // RNE
  return u.s;
}
static __device__ __forceinline__ float bf2f(ushort s) {
  union { float f; uint u; } u;
  u.u = ((uint)s) << 16;
  return u.f;
}
static __device__ __forceinline__ bf16x8 cvt8(const float* v) {
  bf16x8 r;
  #pragma unroll
  for (int i = 0; i < 4; i++) {
    union { __hip_bfloat162 h; short2 s; } u;
    u.h = __float22bfloat162_rn(make_float2(v[2 * i], v[2 * i + 1]));
    r[2 * i] = u.s.x; r[2 * i + 1] = u.s.y;
  }
  return r;
}
static __device__ __forceinline__ void split8(const float* v, bf16x8& hi, bf16x8& lo) {
  hi = cvt8(v);
  float res[8];
  #pragma unroll
  for (int i = 0; i < 8; i++) res[i] = v[i] - bf2f((ushort)hi[i]);
  lo = cvt8(res);
}

// ---------------------------------------------------------------------------
// mono_kernel — cooperative, grid 256 x 512 (1 block/CU, 8 waves).
// Block idx -> (mb = idx>>4, chunk = idx&15): owns 128 rows of tensor mb.
// Stage A: load rows -> xs; inv inline; transposed split-bf16 T; MFMA partial
//          M_chunk = (s.h)^T(s.h) -> Mpart (fp32).
// grid.sync
// Stage B: reduce 16 partials -> Mi (split-bf16, LDS-ready layout).
// grid.sync
// Stage C: x from xs (registers), T <- Mi; y = inv*(x@M); T <- W2(wm);
//          fm epilogue -> out. ys aliases xs (row-private per wave).
// ---------------------------------------------------------------------------
__global__ __launch_bounds__(512, 2) void mono_kernel(
    const float* __restrict__ h1, const float* __restrict__ h2,
    const float* __restrict__ wm, float* __restrict__ Mpart,
    ushort* __restrict__ Mi, float* __restrict__ out) {
  __shared__ float xs[128 * 132];   // 67584 B; reused as ys in stage C
  __shared__ ushort T[128 * 264];   // 67584 B
  __shared__ float invs[128];
  __shared__ float sS[128];

  cg::grid_group grid = cg::this_grid();

  int idx = blockIdx.x;            // 0..255
  int chunk = idx & 15;
  int mb = idx >> 4;               // 0..15
  int b = mb & 7;
  int which = mb >> 3;
  const float* src = (which ? h2 : h1) + ((size_t)b * Nn + chunk * 128) * Hh;
  int t = threadIdx.x;
  int lane = t & 63, w = t >> 6;
  int m = lane & 15, q = lane >> 4;

  // ---- Stage A: stage 128 rows -> xs ----
  #pragma unroll
  for (int i = 0; i < 8; i++) {
    int u = t + 512 * i;           // 0..4095 float4 units
    int r = u >> 5, c = (u & 31) << 2;
    *(float4*)&xs[r * 132 + c] = *(const float4*)(src + (size_t)r * Hh + c);
  }
  __syncthreads();

  // norms: 4 threads per row
  {
    int r = t >> 2, part = t & 3;
    float ss = 0.f;
    #pragma unroll
    for (int i = 0; i < 8; i++) {
      float4 v = *(float4*)&xs[r * 132 + part * 32 + i * 4];
      ss += v.x * v.x + v.y * v.y + v.z * v.z + v.w * v.w;
    }
    ss += __shfl_xor(ss, 1, 64);
    ss += __shfl_xor(ss, 2, 64);
    if (part == 0) {
      float inv = 1.0f / fmaxf(sqrtf(ss), EPS);
      invs[r] = inv;
      sS[r] = sqrtf(inv);
    }
  }
  __syncthreads();

  // transpose + scale + split: T[c][n hi | n lo]
  {
    int c = t & 127, rh = t >> 7;        // rh 0..3 -> rows rh*32..+31
    #pragma unroll
    for (int j = 0; j < 16; j++) {
      int r0 = rh * 32 + 2 * j;
      float v0 = xs[r0 * 132 + c] * sS[r0];
      float v1 = xs[(r0 + 1) * 132 + c] * sS[r0 + 1];
      ushort hh0 = f2bf(v0), hh1 = f2bf(v1);
      ushort ll0 = f2bf(v0 - bf2f(hh0)), ll1 = f2bf(v1 - bf2f(hh1));
      ushort2 uh; uh.x = hh0; uh.y = hh1;
      ushort2 ul; ul.x = ll0; ul.y = ll1;
      *(ushort2*)&T[c * 264 + r0] = uh;
      *(ushort2*)&T[c * 264 + 128 + r0] = ul;
    }
  }
  __syncthreads();

  // GEMM: wave w owns M rows [w*16, w*16+16)
  {
    f32x4 acc[8];
    #pragma unroll
    for (int tc = 0; tc < 8; tc++) acc[tc] = (f32x4){0.f, 0.f, 0.f, 0.f};
    #pragma unroll
    for (int ks = 0; ks < 4; ks++) {
      int n0 = ks * 32 + q * 8;
      int cA = w * 16 + m;
      bf16x8 Ah = *(bf16x8*)&T[cA * 264 + n0];
      bf16x8 Al = *(bf16x8*)&T[cA * 264 + 128 + n0];
      #pragma unroll
      for (int tc = 0; tc < 8; tc++) {
        int cB = tc * 16 + m;
        bf16x8 Bh = *(bf16x8*)&T[cB * 264 + n0];
        bf16x8 Bl = *(bf16x8*)&T[cB * 264 + 128 + n0];
        acc[tc] = MFMA16(Ah, Bh, acc[tc]);
        acc[tc] = MFMA16(Ah, Bl, acc[tc]);
        acc[tc] = MFMA16(Al, Bh, acc[tc]);
      }
    }
    float* outp = Mpart + ((size_t)mb * 16 + chunk) * 16384;
    #pragma unroll
    for (int tc = 0; tc < 8; tc++)
      #pragma unroll
      for (int rg = 0; rg < 4; rg++) {
        int row = w * 16 + q * 4 + rg;
        outp[row * 128 + tc * 16 + m] = acc[tc][rg];
      }
  }

  grid.sync();

  // ---- Stage B: reduce partials -> Mi[mb][k][hi 0..127 | lo 128..255] ----
  {
    int tid = idx * 512 + t;             // 0..131071
    #pragma unroll
    for (int rep = 0; rep < 2; rep++) {
      int e = tid + rep * 131072;        // 0..262143
      int mb2 = e >> 14;
      int rem = e & 16383;
      int k = rem >> 7, h = rem & 127;
      const float* p = Mpart + (size_t)mb2 * 16 * 16384 + rem;
      float s = 0.f;
      #pragma unroll
      for (int c = 0; c < 16; c++) s += p[(size_t)c * 16384];
      ushort hi = f2bf(s);
      Mi[(size_t)mb2 * 32768 + k * 256 + h] = hi;
      Mi[(size_t)mb2 * 32768 + k * 256 + 128 + h] = f2bf(s - bf2f(hi));
    }
  }

  grid.sync();

  // ---- Stage C ----
  // x rows are still in xs; inv still in invs. Load x -> registers.
  int rb = w * 16;
  float xv[4][8];
  #pragma unroll
  for (int ks = 0; ks < 4; ks++) {
    int k0 = ks * 32 + q * 8;
    *(float4*)&xv[ks][0] = *(float4*)&xs[(rb + m) * 132 + k0];
    *(float4*)&xv[ks][4] = *(float4*)&xs[(rb + m) * 132 + k0 + 4];
  }

  // T <- Mi of the OTHER tensor, same batch
  {
    const ushort* Msrc = Mi + (size_t)((which ^ 1) * 8 + b) * 32768;
    #pragma unroll
    for (int i = 0; i < 8; i++) {
      int u = t + 512 * i;               // 0..4095 16B units
      int row = u >> 5, seg = u & 31;
      *(bf16x8*)&T[row * 264 + seg * 8] = *(const bf16x8*)&Msrc[u * 8];
    }
  }
  __syncthreads();

  float* ys = xs;    // alias: safe, each wave reads/writes only its own rows

  // phase 1: y = (x @ M) * inv
  {
    f32x4 acc[8];
    #pragma unroll
    for (int nt = 0; nt < 8; nt++) acc[nt] = (f32x4){0.f, 0.f, 0.f, 0.f};
    #pragma unroll
    for (int ks = 0; ks < 4; ks++) {
      int k0 = ks * 32 + q * 8;
      bf16x8 xh, xl;
      split8(xv[ks], xh, xl);
      #pragma unroll
      for (int nt = 0; nt < 8; nt++) {
        int cB = nt * 16 + m;
        bf16x8 Bh = *(bf16x8*)&T[cB * 264 + k0];
        bf16x8 Bl = *(bf16x8*)&T[cB * 264 + 128 + k0];
        acc[nt] = MFMA16(xh, Bh, acc[nt]);
        acc[nt] = MFMA16(xh, Bl, acc[nt]);
        acc[nt] = MFMA16(xl, Bh, acc[nt]);
      }
    }
    #pragma unroll
    for (int nt = 0; nt < 8; nt++)
      #pragma unroll
      for (int rg = 0; rg < 4; rg++) {
        int row = rb + q * 4 + rg;
        ys[row * 132 + nt * 16 + m] = acc[nt][rg] * invs[row];
      }
  }
  __syncthreads();   // everyone done reading T(Mi)

  // T <- W2 = wm^2 (hi/lo split), computed in-kernel
  #pragma unroll
  for (int i = 0; i < 16; i++) {
    int u = t + 512 * i;                 // pair id 0..8191
    int r = u >> 6, c = (u & 63) * 2;
    float2 w2 = *(const float2*)(wm + r * 128 + c);
    float v0 = w2.x * w2.x, v1 = w2.y * w2.y;
    ushort hh0 = f2bf(v0), hh1 = f2bf(v1);
    ushort ll0 = f2bf(v0 - bf2f(hh0)), ll1 = f2bf(v1 - bf2f(hh1));
    ushort2 uh; uh.x = hh0; uh.y = hh1;
    ushort2 ul; ul.x = ll0; ul.y = ll1;
    *(ushort2*)&T[r * 264 + c] = uh;
    *(ushort2*)&T[r * 264 + 128 + c] = ul;
  }
  __syncthreads();

  // phase 2: fm epilogue
  f32x4 aN[8], aX[8], aY[8];
  #pragma unroll
  for (int nt = 0; nt < 8; nt++) {
    aN[nt] = (f32x4){0.f, 0.f, 0.f, 0.f};
    aX[nt] = (f32x4){0.f, 0.f, 0.f, 0.f};
    aY[nt] = (f32x4){0.f, 0.f, 0.f, 0.f};
  }
  #pragma unroll
  for (int ks = 0; ks < 4; ks++) {
    int k0 = ks * 32 + q * 8;
    float yv[8], pxy[8], pxx[8], pyy[8];
    *(float4*)&yv[0] = *(float4*)&ys[(rb + m) * 132 + k0];
    *(float4*)&yv[4] = *(float4*)&ys[(rb + m) * 132 + k0 + 4];
    #pragma unroll
    for (int i = 0; i < 8; i++) {
      float xf = xv[ks][i];
      pxy[i] = xf * yv[i];
      pxx[i] = xf * xf;
      pyy[i] = yv[i] * yv[i];
    }
    bf16x8 xyh, xyl;
    split8(pxy, xyh, xyl);
    bf16x8 xxh = cvt8(pxx);
    bf16x8 yyh = cvt8(pyy);
    #pragma unroll
    for (int nt = 0; nt < 8; nt++) {
      int cB = nt * 16 + m;
      bf16x8 wh = *(bf16x8*)&T[cB * 264 + k0];
      bf16x8 wl = *(bf16x8*)&T[cB * 264 + 128 + k0];
      aN[nt] = MFMA16(xyh, wh, aN[nt]);
      aN[nt] = MFMA16(xyh, wl, aN[nt]);
      aN[nt] = MFMA16(xyl, wh, aN[nt]);
      aX[nt] = MFMA16(xxh, wh, aX[nt]);
      aX[nt] = MFMA16(xxh, wl, aX[nt]);
      aY[nt] = MFMA16(yyh, wh, aY[nt]);
      aY[nt] = MFMA16(yyh, wl, aY[nt]);
    }
  }

  float* ob = out + ((size_t)mb * Nn + chunk * 128) * Hh;  // out[mb][n][h]
  #pragma unroll
  for (int nt = 0; nt < 8; nt++)
    #pragma unroll
    for (int rg = 0; rg < 4; rg++) {
      int row = rb + q * 4 + rg;
      float dx = fmaxf(sqrtf(fmaxf(aX[nt][rg], 0.f)), EPS);
      float dy = fmaxf(sqrtf(fmaxf(aY[nt][rg], 0.f)), EPS);
      ob[(size_t)row * Hh + nt * 16 + m] = aN[nt][rg] / (dx * dy);
    }
}

// ---------------------------------------------------------------------------
extern "C" void kernel_launch(void* const* d_in, const int* in_sizes, int n_in,
                              void* d_out, int out_size, void* d_ws, size_t ws_size,
                              hipStream_t stream) {
  const float* h1 = (const float*)d_in[0];
  const float* h2 = (const float*)d_in[1];
  const float* wm = (const float*)d_in[2];
  float* out = (float*)d_out;

  char* ws = (char*)d_ws;
  float* Mpart = (float*)ws;                 // 16*16*16384*4 = 16 MiB
  ushort* Mi   = (ushort*)(ws + 16777216);   // 16*32768*2    = 1 MiB

  void* args[] = {(void*)&h1, (void*)&h2, (void*)&wm,
                  (void*)&Mpart, (void*)&Mi, (void*)&out};
  hipLaunchCooperativeKernel((const void*)mono_kernel, dim3(256), dim3(512),
                             args, 0, stream);
}

// Round 7
// 99.393 us; speedup vs baseline: 1.7668x; 1.7668x over previous
//
#include <hip/hip_runtime.h>
#include <hip/hip_bf16.h>
#include <math.h>

#define EPS 1e-8f

constexpr int Bb = 8, Nn = 2048, Hh = 128;
constexpr int BN = Bb * Nn;      // 16384 rows per tensor
constexpr int CCH = 16;          // split-K chunks for matp

typedef __attribute__((ext_vector_type(8))) short bf16x8;
typedef __attribute__((ext_vector_type(4))) float f32x4;

#define MFMA16(a, b, c) __builtin_amdgcn_mfma_f32_16x16x32_bf16(a, b, c, 0, 0, 0)

static __device__ __forceinline__ ushort f2bf(float f) {
  union { __hip_bfloat16 h; ushort s; } u;
  u.h = __float2bfloat16(f);   // RNE
  return u.s;
}
static __device__ __forceinline__ float bf2f(ushort s) {
  union { float f; uint u; } u;
  u.u = ((uint)s) << 16;
  return u.f;
}
static __device__ __forceinline__ bf16x8 cvt8(const float* v) {
  bf16x8 r;
  #pragma unroll
  for (int i = 0; i < 4; i++) {
    union { __hip_bfloat162 h; short2 s; } u;
    u.h = __float22bfloat162_rn(make_float2(v[2 * i], v[2 * i + 1]));
    r[2 * i] = u.s.x; r[2 * i + 1] = u.s.y;
  }
  return r;
}
static __device__ __forceinline__ void split8(const float* v, bf16x8& hi, bf16x8& lo) {
  hi = cvt8(v);
  float res[8];
  #pragma unroll
  for (int i = 0; i < 8; i++) res[i] = v[i] - bf2f((ushort)hi[i]);
  lo = cvt8(res);
}

// ---------------------------------------------------------------------------
// Kernel 1: matp — M_chunk = (s.h)^T (s.h), 128 rows per block, 512 threads.
// Single-pass staging; inv inline; transposed split-bf16 T; 8 waves x 16
// M-rows GEMM; fp32 partials to Mpart. grid: idx = mb*CCH + chunk.
// ---------------------------------------------------------------------------
__global__ __launch_bounds__(512) void matp_kernel(const float* __restrict__ h1,
                                                   const float* __restrict__ h2,
                                                   float* __restrict__ inv_out,
                                                   float* __restrict__ Mpart) {
  __shared__ float xs[128 * 132];
  __shared__ ushort T[128 * 264];
  __shared__ float invs[128];
  __shared__ float sS[128];

  int idx = blockIdx.x;
  int chunk = idx % CCH;
  int mb = idx / CCH;
  int b = mb & 7;
  int mat = mb >> 3;
  const float* src = (mat ? h2 : h1) + ((size_t)b * Nn + chunk * 128) * Hh;
  float* invp = inv_out + mat * BN + b * Nn + chunk * 128;
  int t = threadIdx.x;
  int lane = t & 63, w = t >> 6;
  int m = lane & 15, q = lane >> 4;

  // stage 128 rows (one pass, 8 x 512 float4)
  #pragma unroll
  for (int i = 0; i < 8; i++) {
    int u = t + 512 * i;
    int r = u >> 5, c = (u & 31) << 2;
    *(float4*)&xs[r * 132 + c] = *(const float4*)(src + (size_t)r * Hh + c);
  }
  __syncthreads();

  // norms: 4 threads per row
  {
    int r = t >> 2, part = t & 3;
    float ss = 0.f;
    #pragma unroll
    for (int i = 0; i < 8; i++) {
      float4 v = *(float4*)&xs[r * 132 + part * 32 + i * 4];
      ss += v.x * v.x + v.y * v.y + v.z * v.z + v.w * v.w;
    }
    ss += __shfl_xor(ss, 1, 64);
    ss += __shfl_xor(ss, 2, 64);
    if (part == 0) {
      float inv = 1.0f / fmaxf(sqrtf(ss), EPS);
      invs[r] = inv;
      sS[r] = sqrtf(inv);
    }
  }
  __syncthreads();

  // transpose + scale + split: T[c][n hi 0..127 | n lo 128..255]
  {
    int c = t & 127, rh = t >> 7;
    #pragma unroll
    for (int j = 0; j < 16; j++) {
      int r0 = rh * 32 + 2 * j;
      float v0 = xs[r0 * 132 + c] * sS[r0];
      float v1 = xs[(r0 + 1) * 132 + c] * sS[r0 + 1];
      ushort hh0 = f2bf(v0), hh1 = f2bf(v1);
      ushort ll0 = f2bf(v0 - bf2f(hh0)), ll1 = f2bf(v1 - bf2f(hh1));
      ushort2 uh; uh.x = hh0; uh.y = hh1;
      ushort2 ul; ul.x = ll0; ul.y = ll1;
      *(ushort2*)&T[c * 264 + r0] = uh;
      *(ushort2*)&T[c * 264 + 128 + r0] = ul;
    }
  }
  __syncthreads();

  // GEMM: wave w owns M rows [w*16, w*16+16)
  f32x4 acc[8];
  #pragma unroll
  for (int tc = 0; tc < 8; tc++) acc[tc] = (f32x4){0.f, 0.f, 0.f, 0.f};
  #pragma unroll
  for (int ks = 0; ks < 4; ks++) {
    int n0 = ks * 32 + q * 8;
    int cA = w * 16 + m;
    bf16x8 Ah = *(bf16x8*)&T[cA * 264 + n0];
    bf16x8 Al = *(bf16x8*)&T[cA * 264 + 128 + n0];
    #pragma unroll
    for (int tc = 0; tc < 8; tc++) {
      int cB = tc * 16 + m;
      bf16x8 Bh = *(bf16x8*)&T[cB * 264 + n0];
      bf16x8 Bl = *(bf16x8*)&T[cB * 264 + 128 + n0];
      acc[tc] = MFMA16(Ah, Bh, acc[tc]);
      acc[tc] = MFMA16(Ah, Bl, acc[tc]);
      acc[tc] = MFMA16(Al, Bh, acc[tc]);
    }
  }
  if (t < 128) invp[t] = invs[t];
  float* outp = Mpart + ((size_t)mb * CCH + chunk) * 16384;
  #pragma unroll
  for (int tc = 0; tc < 8; tc++)
    #pragma unroll
    for (int rg = 0; rg < 4; rg++) {
      int row = w * 16 + q * 4 + rg;
      outp[row * 128 + tc * 16 + m] = acc[tc][rg];
    }
}

// ---------------------------------------------------------------------------
// Kernel 2: reduce partials -> Mi[mb][k][hi 0..127 | lo 128..255] (LDS-ready)
// ---------------------------------------------------------------------------
__global__ __launch_bounds__(256) void matr_kernel(const float* __restrict__ Mpart,
                                                   ushort* __restrict__ Mi) {
  int gid = blockIdx.x * 256 + threadIdx.x;   // 16*16384
  int mb = gid >> 14;
  int e = gid & 16383;
  int k = e >> 7, h = e & 127;
  const float* p = Mpart + (size_t)mb * CCH * 16384 + e;
  float s = 0.f;
  #pragma unroll
  for (int c = 0; c < CCH; c++) s += p[(size_t)c * 16384];
  ushort hi = f2bf(s);
  Mi[(size_t)mb * 32768 + k * 256 + h] = hi;
  Mi[(size_t)mb * 32768 + k * 256 + 128 + h] = f2bf(s - bf2f(hi));
}

// ---------------------------------------------------------------------------
// Kernel 3: fused2 — phase 1: y = inv*(x@M) with Mi in LDS, x in registers;
// phase 2: re-stage LDS with W2 (from wm in-kernel), fm epilogue.
// 128 rows/block, 512 threads (8 waves x 16 rows), 256 blocks = 1/CU.
// ---------------------------------------------------------------------------
__global__ __launch_bounds__(512, 2) void fused2_kernel(
    const float* __restrict__ h1, const float* __restrict__ h2,
    const float* __restrict__ inv, const ushort* __restrict__ Mi,
    const float* __restrict__ wm, float* __restrict__ out) {
  __shared__ ushort T[128 * 264];
  __shared__ float ys[128 * 132];
  __shared__ float invs[128];

  int g0 = blockIdx.x * 128;
  int which = g0 >> 14, b = (g0 >> 11) & 7, n0 = g0 & 2047;
  const float* xsrc = which ? h2 : h1;
  const ushort* Msrc = Mi + (size_t)((which ^ 1) * 8 + b) * 32768;
  int t = threadIdx.x;

  #pragma unroll
  for (int i = 0; i < 8; i++) {
    int u = t + 512 * i;
    int row = u >> 5, seg = u & 31;
    *(bf16x8*)&T[row * 264 + seg * 8] = *(const bf16x8*)&Msrc[u * 8];
  }
  if (t < 128) invs[t] = inv[which * BN + b * Nn + n0 + t];
  __syncthreads();

  int lane = t & 63, m = lane & 15, q = lane >> 4, rb = (t >> 6) * 16;
  const float* xrow = xsrc + ((size_t)b * Nn + n0 + rb + m) * Hh;

  float xv[4][8];
  #pragma unroll
  for (int ks = 0; ks < 4; ks++) {
    int k0 = ks * 32 + q * 8;
    *(float4*)&xv[ks][0] = *(const float4*)(xrow + k0);
    *(float4*)&xv[ks][4] = *(const float4*)(xrow + k0 + 4);
  }

  // ---- phase 1: y = (x @ M) * inv ----
  {
    f32x4 acc[8];
    #pragma unroll
    for (int nt = 0; nt < 8; nt++) acc[nt] = (f32x4){0.f, 0.f, 0.f, 0.f};
    #pragma unroll
    for (int ks = 0; ks < 4; ks++) {
      int k0 = ks * 32 + q * 8;
      bf16x8 xh, xl;
      split8(xv[ks], xh, xl);
      #pragma unroll
      for (int nt = 0; nt < 8; nt++) {
        int cB = nt * 16 + m;
        bf16x8 Bh = *(bf16x8*)&T[cB * 264 + k0];
        bf16x8 Bl = *(bf16x8*)&T[cB * 264 + 128 + k0];
        acc[nt] = MFMA16(xh, Bh, acc[nt]);
        acc[nt] = MFMA16(xh, Bl, acc[nt]);
        acc[nt] = MFMA16(xl, Bh, acc[nt]);
      }
    }
    #pragma unroll
    for (int nt = 0; nt < 8; nt++)
      #pragma unroll
      for (int rg = 0; rg < 4; rg++) {
        int row = rb + q * 4 + rg;
        ys[row * 132 + nt * 16 + m] = acc[nt][rg] * invs[row];
      }
  }
  __syncthreads();   // everyone done reading T(Mi)

  // T <- W2 = wm^2 (hi/lo split)
  #pragma unroll
  for (int i = 0; i < 16; i++) {
    int u = t + 512 * i;
    int r = u >> 6, c = (u & 63) * 2;
    float2 w2 = *(const float2*)(wm + r * 128 + c);
    float v0 = w2.x * w2.x, v1 = w2.y * w2.y;
    ushort hh0 = f2bf(v0), hh1 = f2bf(v1);
    ushort ll0 = f2bf(v0 - bf2f(hh0)), ll1 = f2bf(v1 - bf2f(hh1));
    ushort2 uh; uh.x = hh0; uh.y = hh1;
    ushort2 ul; ul.x = ll0; ul.y = ll1;
    *(ushort2*)&T[r * 264 + c] = uh;
    *(ushort2*)&T[r * 264 + 128 + c] = ul;
  }
  __syncthreads();

  // ---- phase 2: fm epilogue ----
  f32x4 aN[8], aX[8], aY[8];
  #pragma unroll
  for (int nt = 0; nt < 8; nt++) {
    aN[nt] = (f32x4){0.f, 0.f, 0.f, 0.f};
    aX[nt] = (f32x4){0.f, 0.f, 0.f, 0.f};
    aY[nt] = (f32x4){0.f, 0.f, 0.f, 0.f};
  }
  #pragma unroll
  for (int ks = 0; ks < 4; ks++) {
    int k0 = ks * 32 + q * 8;
    float yv[8], pxy[8], pxx[8], pyy[8];
    *(float4*)&yv[0] = *(const float4*)&ys[(rb + m) * 132 + k0];
    *(float4*)&yv[4] = *(const float4*)&ys[(rb + m) * 132 + k0 + 4];
    #pragma unroll
    for (int i = 0; i < 8; i++) {
      float xf = xv[ks][i];
      pxy[i] = xf * yv[i];
      pxx[i] = xf * xf;
      pyy[i] = yv[i] * yv[i];
    }
    bf16x8 xyh, xyl;
    split8(pxy, xyh, xyl);
    bf16x8 xxh = cvt8(pxx);
    bf16x8 yyh = cvt8(pyy);
    #pragma unroll
    for (int nt = 0; nt < 8; nt++) {
      int cB = nt * 16 + m;
      bf16x8 wh = *(bf16x8*)&T[cB * 264 + k0];
      bf16x8 wl = *(bf16x8*)&T[cB * 264 + 128 + k0];
      aN[nt] = MFMA16(xyh, wh, aN[nt]);
      aN[nt] = MFMA16(xyh, wl, aN[nt]);
      aN[nt] = MFMA16(xyl, wh, aN[nt]);
      aX[nt] = MFMA16(xxh, wh, aX[nt]);
      aX[nt] = MFMA16(xxh, wl, aX[nt]);
      aY[nt] = MFMA16(yyh, wh, aY[nt]);
      aY[nt] = MFMA16(yyh, wl, aY[nt]);
    }
  }

  float* ob = out + (size_t)g0 * Hh;
  #pragma unroll
  for (int nt = 0; nt < 8; nt++)
    #pragma unroll
    for (int rg = 0; rg < 4; rg++) {
      int row = rb + q * 4 + rg;
      float dx = fmaxf(sqrtf(fmaxf(aX[nt][rg], 0.f)), EPS);
      float dy = fmaxf(sqrtf(fmaxf(aY[nt][rg], 0.f)), EPS);
      ob[(size_t)row * Hh + nt * 16 + m] = aN[nt][rg] / (dx * dy);
    }
}

// ---------------------------------------------------------------------------
extern "C" void kernel_launch(void* const* d_in, const int* in_sizes, int n_in,
                              void* d_out, int out_size, void* d_ws, size_t ws_size,
                              hipStream_t stream) {
  const float* h1 = (const float*)d_in[0];
  const float* h2 = (const float*)d_in[1];
  const float* wm = (const float*)d_in[2];
  float* out = (float*)d_out;

  char* ws = (char*)d_ws;
  float* inv   = (float*)ws;                 // 2*16384*4    = 131072 B
  ushort* Mi   = (ushort*)(ws + 131072);     // 16*32768*2   = 1 MiB
  float* Mpart = (float*)(ws + 1179648);     // 16*16*16384*4 = 16 MiB

  matp_kernel<<<16 * CCH, 512, 0, stream>>>(h1, h2, inv, Mpart);
  matr_kernel<<<16 * 16384 / 256, 256, 0, stream>>>(Mpart, Mi);
  fused2_kernel<<<2 * BN / 128, 512, 0, stream>>>(h1, h2, inv, Mi, wm, out);
}

// Round 8
// 99.390 us; speedup vs baseline: 1.7668x; 1.0000x over previous
//
#include <hip/hip_runtime.h>
#include <hip/hip_bf16.h>
#include <math.h>

#define EPS 1e-8f

constexpr int Bb = 8, Nn = 2048, Hh = 128;
constexpr int BN = Bb * Nn;      // 16384 rows per tensor
constexpr int CCH = 16;          // split-K chunks for matp
constexpr int TS = 280;          // T row stride (ushorts): 140 dw = 12 mod 32 banks,
                                 // 16B-aligned; 264 (4 mod 32) caused 8-way conflicts

typedef __attribute__((ext_vector_type(8))) short bf16x8;
typedef __attribute__((ext_vector_type(4))) float f32x4;

#define MFMA16(a, b, c) __builtin_amdgcn_mfma_f32_16x16x32_bf16(a, b, c, 0, 0, 0)

static __device__ __forceinline__ ushort f2bf(float f) {
  union { __hip_bfloat16 h; ushort s; } u;
  u.h = __float2bfloat16(f);   // RNE
  return u.s;
}
static __device__ __forceinline__ float bf2f(ushort s) {
  union { float f; uint u; } u;
  u.u = ((uint)s) << 16;
  return u.f;
}
static __device__ __forceinline__ bf16x8 cvt8(const float* v) {
  bf16x8 r;
  #pragma unroll
  for (int i = 0; i < 4; i++) {
    union { __hip_bfloat162 h; short2 s; } u;
    u.h = __float22bfloat162_rn(make_float2(v[2 * i], v[2 * i + 1]));
    r[2 * i] = u.s.x; r[2 * i + 1] = u.s.y;
  }
  return r;
}
static __device__ __forceinline__ void split8(const float* v, bf16x8& hi, bf16x8& lo) {
  hi = cvt8(v);
  float res[8];
  #pragma unroll
  for (int i = 0; i < 8; i++) res[i] = v[i] - bf2f((ushort)hi[i]);
  lo = cvt8(res);
}

// ---------------------------------------------------------------------------
// Kernel 1: matp — M_chunk = (s.h)^T (s.h), 128 rows per block, 512 threads.
// Single-pass staging; inv inline; transposed split-bf16 T; 8 waves x 16
// M-rows GEMM; fp32 partials to Mpart. grid: idx = mb*CCH + chunk.
// ---------------------------------------------------------------------------
__global__ __launch_bounds__(512) void matp_kernel(const float* __restrict__ h1,
                                                   const float* __restrict__ h2,
                                                   float* __restrict__ inv_out,
                                                   float* __restrict__ Mpart) {
  __shared__ float xs[128 * 132];
  __shared__ ushort T[128 * TS];
  __shared__ float invs[128];
  __shared__ float sS[128];

  int idx = blockIdx.x;
  int chunk = idx % CCH;
  int mb = idx / CCH;
  int b = mb & 7;
  int mat = mb >> 3;
  const float* src = (mat ? h2 : h1) + ((size_t)b * Nn + chunk * 128) * Hh;
  float* invp = inv_out + mat * BN + b * Nn + chunk * 128;
  int t = threadIdx.x;
  int lane = t & 63, w = t >> 6;
  int m = lane & 15, q = lane >> 4;

  // stage 128 rows (one pass, 8 x 512 float4)
  #pragma unroll
  for (int i = 0; i < 8; i++) {
    int u = t + 512 * i;
    int r = u >> 5, c = (u & 31) << 2;
    *(float4*)&xs[r * 132 + c] = *(const float4*)(src + (size_t)r * Hh + c);
  }
  __syncthreads();

  // norms: 4 threads per row
  {
    int r = t >> 2, part = t & 3;
    float ss = 0.f;
    #pragma unroll
    for (int i = 0; i < 8; i++) {
      float4 v = *(float4*)&xs[r * 132 + part * 32 + i * 4];
      ss += v.x * v.x + v.y * v.y + v.z * v.z + v.w * v.w;
    }
    ss += __shfl_xor(ss, 1, 64);
    ss += __shfl_xor(ss, 2, 64);
    if (part == 0) {
      float inv = 1.0f / fmaxf(sqrtf(ss), EPS);
      invs[r] = inv;
      sS[r] = sqrtf(inv);
    }
  }
  __syncthreads();

  // transpose + scale + split: T[c][n hi 0..127 | n lo 128..255]
  {
    int c = t & 127, rh = t >> 7;
    #pragma unroll
    for (int j = 0; j < 16; j++) {
      int r0 = rh * 32 + 2 * j;
      float v0 = xs[r0 * 132 + c] * sS[r0];
      float v1 = xs[(r0 + 1) * 132 + c] * sS[r0 + 1];
      ushort hh0 = f2bf(v0), hh1 = f2bf(v1);
      ushort ll0 = f2bf(v0 - bf2f(hh0)), ll1 = f2bf(v1 - bf2f(hh1));
      ushort2 uh; uh.x = hh0; uh.y = hh1;
      ushort2 ul; ul.x = ll0; ul.y = ll1;
      *(ushort2*)&T[c * TS + r0] = uh;
      *(ushort2*)&T[c * TS + 128 + r0] = ul;
    }
  }
  __syncthreads();

  // GEMM: wave w owns M rows [w*16, w*16+16)
  f32x4 acc[8];
  #pragma unroll
  for (int tc = 0; tc < 8; tc++) acc[tc] = (f32x4){0.f, 0.f, 0.f, 0.f};
  #pragma unroll
  for (int ks = 0; ks < 4; ks++) {
    int n0 = ks * 32 + q * 8;
    int cA = w * 16 + m;
    bf16x8 Ah = *(bf16x8*)&T[cA * TS + n0];
    bf16x8 Al = *(bf16x8*)&T[cA * TS + 128 + n0];
    #pragma unroll
    for (int tc = 0; tc < 8; tc++) {
      int cB = tc * 16 + m;
      bf16x8 Bh = *(bf16x8*)&T[cB * TS + n0];
      bf16x8 Bl = *(bf16x8*)&T[cB * TS + 128 + n0];
      acc[tc] = MFMA16(Ah, Bh, acc[tc]);
      acc[tc] = MFMA16(Ah, Bl, acc[tc]);
      acc[tc] = MFMA16(Al, Bh, acc[tc]);
    }
  }
  if (t < 128) invp[t] = invs[t];
  float* outp = Mpart + ((size_t)mb * CCH + chunk) * 16384;
  #pragma unroll
  for (int tc = 0; tc < 8; tc++)
    #pragma unroll
    for (int rg = 0; rg < 4; rg++) {
      int row = w * 16 + q * 4 + rg;
      outp[row * 128 + tc * 16 + m] = acc[tc][rg];
    }
}

// ---------------------------------------------------------------------------
// Kernel 2: reduce partials -> Mi[mb][k][hi 0..127 | lo 128..255] (LDS-ready)
// ---------------------------------------------------------------------------
__global__ __launch_bounds__(256) void matr_kernel(const float* __restrict__ Mpart,
                                                   ushort* __restrict__ Mi) {
  int gid = blockIdx.x * 256 + threadIdx.x;   // 16*16384
  int mb = gid >> 14;
  int e = gid & 16383;
  int k = e >> 7, h = e & 127;
  const float* p = Mpart + (size_t)mb * CCH * 16384 + e;
  float s = 0.f;
  #pragma unroll
  for (int c = 0; c < CCH; c++) s += p[(size_t)c * 16384];
  ushort hi = f2bf(s);
  Mi[(size_t)mb * 32768 + k * 256 + h] = hi;
  Mi[(size_t)mb * 32768 + k * 256 + 128 + h] = f2bf(s - bf2f(hi));
}

// ---------------------------------------------------------------------------
// Kernel 3: fused2 — phase 1: y = inv*(x@M) with Mi in LDS, x in registers;
// phase 2: re-stage LDS with W2 (from wm in-kernel), fm epilogue.
// 128 rows/block, 512 threads (8 waves x 16 rows), 256 blocks = 1/CU.
// ---------------------------------------------------------------------------
__global__ __launch_bounds__(512, 2) void fused2_kernel(
    const float* __restrict__ h1, const float* __restrict__ h2,
    const float* __restrict__ inv, const ushort* __restrict__ Mi,
    const float* __restrict__ wm, float* __restrict__ out) {
  __shared__ ushort T[128 * TS];
  __shared__ float ys[128 * 132];
  __shared__ float invs[128];

  int g0 = blockIdx.x * 128;
  int which = g0 >> 14, b = (g0 >> 11) & 7, n0 = g0 & 2047;
  const float* xsrc = which ? h2 : h1;
  const ushort* Msrc = Mi + (size_t)((which ^ 1) * 8 + b) * 32768;
  int t = threadIdx.x;

  #pragma unroll
  for (int i = 0; i < 8; i++) {
    int u = t + 512 * i;
    int row = u >> 5, seg = u & 31;
    *(bf16x8*)&T[row * TS + seg * 8] = *(const bf16x8*)&Msrc[u * 8];
  }
  if (t < 128) invs[t] = inv[which * BN + b * Nn + n0 + t];
  __syncthreads();

  int lane = t & 63, m = lane & 15, q = lane >> 4, rb = (t >> 6) * 16;
  const float* xrow = xsrc + ((size_t)b * Nn + n0 + rb + m) * Hh;

  float xv[4][8];
  #pragma unroll
  for (int ks = 0; ks < 4; ks++) {
    int k0 = ks * 32 + q * 8;
    *(float4*)&xv[ks][0] = *(const float4*)(xrow + k0);
    *(float4*)&xv[ks][4] = *(const float4*)(xrow + k0 + 4);
  }

  // ---- phase 1: y = (x @ M) * inv ----
  {
    f32x4 acc[8];
    #pragma unroll
    for (int nt = 0; nt < 8; nt++) acc[nt] = (f32x4){0.f, 0.f, 0.f, 0.f};
    #pragma unroll
    for (int ks = 0; ks < 4; ks++) {
      int k0 = ks * 32 + q * 8;
      bf16x8 xh, xl;
      split8(xv[ks], xh, xl);
      #pragma unroll
      for (int nt = 0; nt < 8; nt++) {
        int cB = nt * 16 + m;
        bf16x8 Bh = *(bf16x8*)&T[cB * TS + k0];
        bf16x8 Bl = *(bf16x8*)&T[cB * TS + 128 + k0];
        acc[nt] = MFMA16(xh, Bh, acc[nt]);
        acc[nt] = MFMA16(xh, Bl, acc[nt]);
        acc[nt] = MFMA16(xl, Bh, acc[nt]);
      }
    }
    #pragma unroll
    for (int nt = 0; nt < 8; nt++)
      #pragma unroll
      for (int rg = 0; rg < 4; rg++) {
        int row = rb + q * 4 + rg;
        ys[row * 132 + nt * 16 + m] = acc[nt][rg] * invs[row];
      }
  }
  __syncthreads();   // everyone done reading T(Mi)

  // T <- W2 = wm^2 (hi/lo split)
  #pragma unroll
  for (int i = 0; i < 16; i++) {
    int u = t + 512 * i;
    int r = u >> 6, c = (u & 63) * 2;
    float2 w2 = *(const float2*)(wm + r * 128 + c);
    float v0 = w2.x * w2.x, v1 = w2.y * w2.y;
    ushort hh0 = f2bf(v0), hh1 = f2bf(v1);
    ushort ll0 = f2bf(v0 - bf2f(hh0)), ll1 = f2bf(v1 - bf2f(hh1));
    ushort2 uh; uh.x = hh0; uh.y = hh1;
    ushort2 ul; ul.x = ll0; ul.y = ll1;
    *(ushort2*)&T[r * TS + c] = uh;
    *(ushort2*)&T[r * TS + 128 + c] = ul;
  }
  __syncthreads();

  // ---- phase 2: fm epilogue ----
  f32x4 aN[8], aX[8], aY[8];
  #pragma unroll
  for (int nt = 0; nt < 8; nt++) {
    aN[nt] = (f32x4){0.f, 0.f, 0.f, 0.f};
    aX[nt] = (f32x4){0.f, 0.f, 0.f, 0.f};
    aY[nt] = (f32x4){0.f, 0.f, 0.f, 0.f};
  }
  #pragma unroll
  for (int ks = 0; ks < 4; ks++) {
    int k0 = ks * 32 + q * 8;
    float yv[8], pxy[8], pxx[8], pyy[8];
    *(float4*)&yv[0] = *(const float4*)&ys[(rb + m) * 132 + k0];
    *(float4*)&yv[4] = *(const float4*)&ys[(rb + m) * 132 + k0 + 4];
    #pragma unroll
    for (int i = 0; i < 8; i++) {
      float xf = xv[ks][i];
      pxy[i] = xf * yv[i];
      pxx[i] = xf * xf;
      pyy[i] = yv[i] * yv[i];
    }
    bf16x8 xyh, xyl;
    split8(pxy, xyh, xyl);
    bf16x8 xxh = cvt8(pxx);
    bf16x8 yyh = cvt8(pyy);
    #pragma unroll
    for (int nt = 0; nt < 8; nt++) {
      int cB = nt * 16 + m;
      bf16x8 wh = *(bf16x8*)&T[cB * TS + k0];
      bf16x8 wl = *(bf16x8*)&T[cB * TS + 128 + k0];
      aN[nt] = MFMA16(xyh, wh, aN[nt]);
      aN[nt] = MFMA16(xyh, wl, aN[nt]);
      aN[nt] = MFMA16(xyl, wh, aN[nt]);
      aX[nt] = MFMA16(xxh, wh, aX[nt]);
      aX[nt] = MFMA16(xxh, wl, aX[nt]);
      aY[nt] = MFMA16(yyh, wh, aY[nt]);
      aY[nt] = MFMA16(yyh, wl, aY[nt]);
    }
  }

  float* ob = out + (size_t)g0 * Hh;
  #pragma unroll
  for (int nt = 0; nt < 8; nt++)
    #pragma unroll
    for (int rg = 0; rg < 4; rg++) {
      int row = rb + q * 4 + rg;
      float dx = fmaxf(sqrtf(fmaxf(aX[nt][rg], 0.f)), EPS);
      float dy = fmaxf(sqrtf(fmaxf(aY[nt][rg], 0.f)), EPS);
      ob[(size_t)row * Hh + nt * 16 + m] = aN[nt][rg] / (dx * dy);
    }
}

// ---------------------------------------------------------------------------
extern "C" void kernel_launch(void* const* d_in, const int* in_sizes, int n_in,
                              void* d_out, int out_size, void* d_ws, size_t ws_size,
                              hipStream_t stream) {
  const float* h1 = (const float*)d_in[0];
  const float* h2 = (const float*)d_in[1];
  const float* wm = (const float*)d_in[2];
  float* out = (float*)d_out;

  char* ws = (char*)d_ws;
  float* inv   = (float*)ws;                 // 2*16384*4    = 131072 B
  ushort* Mi   = (ushort*)(ws + 131072);     // 16*32768*2   = 1 MiB
  float* Mpart = (float*)(ws + 1179648);     // 16*16*16384*4 = 16 MiB

  matp_kernel<<<16 * CCH, 512, 0, stream>>>(h1, h2, inv, Mpart);
  matr_kernel<<<16 * 16384 / 256, 256, 0, stream>>>(Mpart, Mi);
  fused2_kernel<<<2 * BN / 128, 512, 0, stream>>>(h1, h2, inv, Mi, wm, out);
}